// Round 24
// baseline (158.773 us; speedup 1.0000x reference)
//
#include <hip/hip_runtime.h>
#include <hip/hip_bf16.h>
#include <math.h>

#define BB   2
#define CC   96
#define C3   288
#define HH   192
#define WWI  192
#define HWQ  (HH*WWI)   // 36864
#define NWH  24
#define NW   576
#define P2   64

typedef float v4f  __attribute__((ext_vector_type(4)));
typedef float f32x4 __attribute__((ext_vector_type(4)));
typedef short s16x8 __attribute__((ext_vector_type(8)));
typedef short s16x4 __attribute__((ext_vector_type(4)));
typedef unsigned short ushort_t;

static __device__ __forceinline__ unsigned short f2bf(float f) {
  __hip_bfloat16 h = __float2bfloat16(f);
  return *reinterpret_cast<unsigned short*>(&h);
}
static __device__ __forceinline__ float bf2f(ushort_t u) {
  union { unsigned u32; float f; } x;
  x.u32 = ((unsigned)u) << 16;
  return x.f;
}

// ---------------- K0: convert both weight arrays to bf16 (one launch) ----------------
__global__ __launch_bounds__(256) void k0_cvtw2(const float* __restrict__ a,
                                                ushort_t* __restrict__ ab, int na,
                                                const float* __restrict__ b,
                                                ushort_t* __restrict__ bb, int nb) {
  int i = blockIdx.x * 256 + threadIdx.x;
  if (i < na) ab[i] = f2bf(a[i]);
  int j = i - na;
  if (j >= 0 && j < nb) bb[j] = f2bf(b[j]);
}

// ---------------- K1: qkv = conv1x1(x), bf16 MFMA GEMM, LDS-shared A-tile ----------------
__global__ __launch_bounds__(384) void k1_qkv(const float* __restrict__ x,
                                              const ushort_t* __restrict__ qwb,
                                              ushort_t* __restrict__ qkv_bf) {
  __shared__ ushort_t XA[64][104];
  const int tid  = threadIdx.x;
  const int lane = tid & 63;
  const int wv   = tid >> 6;       // 0..5
  const int lq   = lane & 15;
  const int g    = lane >> 4;      // 0..3
  const int m0   = blockIdx.x * 64;
  const int b    = m0 / HWQ;
  const int hwb  = m0 % HWQ;
  const int n0   = wv * 48;

#pragma unroll
  for (int it = 0; it < 4; it++) {
    int idx = tid + it * 384;
    int px = idx / 24, c4 = idx % 24;
    v4f xx = *(const v4f*)(x + (size_t)(m0 + px) * 96 + c4 * 4);
    s16x4 st;
#pragma unroll
    for (int t = 0; t < 4; t++) st[t] = (short)f2bf(xx[t]);
    *(s16x4*)&XA[px][c4 * 4] = st;
  }
  __syncthreads();

  const f32x4 zf = {0.f, 0.f, 0.f, 0.f};
  f32x4 acc[4][3];
#pragma unroll
  for (int mt = 0; mt < 4; mt++)
#pragma unroll
    for (int nt = 0; nt < 3; nt++) acc[mt][nt] = zf;

#pragma unroll
  for (int kk = 0; kk < 3; kk++) {
    s16x8 af[4];
#pragma unroll
    for (int mt = 0; mt < 4; mt++)
      af[mt] = *(const s16x8*)&XA[mt * 16 + lq][kk * 32 + g * 8];
    s16x8 bfr[3];
#pragma unroll
    for (int nt = 0; nt < 3; nt++)
      bfr[nt] = *(const s16x8*)(qwb + (size_t)(n0 + nt * 16 + lq) * 96 + kk * 32 + g * 8);
#pragma unroll
    for (int mt = 0; mt < 4; mt++)
#pragma unroll
      for (int nt = 0; nt < 3; nt++)
        acc[mt][nt] = __builtin_amdgcn_mfma_f32_16x16x32_bf16(af[mt], bfr[nt], acc[mt][nt], 0, 0, 0);
  }

  ushort_t* ob = qkv_bf + (size_t)b * C3 * HWQ;
#pragma unroll
  for (int nt = 0; nt < 3; nt++) {
    int o = n0 + nt * 16 + lq;
#pragma unroll
    for (int mt = 0; mt < 4; mt++) {
      s16x4 st;
#pragma unroll
      for (int t = 0; t < 4; t++) st[t] = (short)f2bf(acc[mt][nt][t]);
      *(s16x4*)(ob + (size_t)o * HWQ + hwb + mt * 16 + g * 4) = st;
    }
  }
}

// ---------------- K2: depthwise 3x3 + patchify (+ l2norm for q,k); lean r15 form ----------------
__global__ __launch_bounds__(256) void k2_dw(const ushort_t* __restrict__ qkv_pre,
                                             const float* __restrict__ dww,
                                             ushort_t* __restrict__ qpo, ushort_t* __restrict__ kpo,
                                             ushort_t* __restrict__ vpo) {
  __shared__ float tin[34][40];   // rows -1..32; col j at [.][4+j], edges at [3]/[36]
  int bx  = blockIdx.x;
  int b   = bx / (C3 * 36);
  int rem = bx % (C3 * 36);
  int ch  = rem / 36;
  int tile = rem % 36;
  int ty = tile / 6, tx = tile % 6;
  int tid = threadIdx.x;
  const ushort_t* src = qkv_pre + ((size_t)b * C3 + ch) * HWQ;
  const int h0 = ty * 32 - 1, w0 = tx * 32;

  for (int idx = tid; idx < 340; idx += 256) {
    int r = idx / 10, u = idx - r * 10;
    int h = h0 + r;
    bool hok = (h >= 0 && h < HH);
    if (u < 8) {
      v4f f = {0.f, 0.f, 0.f, 0.f};
      if (hok) {
        s16x4 raw = *(const s16x4*)(src + h * WWI + w0 + u * 4);
#pragma unroll
        for (int t = 0; t < 4; t++) f[t] = bf2f((ushort_t)raw[t]);
      }
      *(v4f*)&tin[r][4 + u * 4] = f;   // 16-B aligned (row stride 160 B)
    } else {
      int w = (u == 8) ? (w0 - 1) : (w0 + 32);
      int cdst = (u == 8) ? 3 : 36;
      float f = 0.f;
      if (hok && w >= 0 && w < WWI) f = bf2f(src[h * WWI + w]);
      tin[r][cdst] = f;
    }
  }
  float wv[9];
#pragma unroll
  for (int i = 0; i < 9; i++) wv[i] = dww[ch * 9 + i];
  __syncthreads();

  const int part = ch / CC, c96 = ch % CC;
  const int bc = b * CC + c96;
  const int cc = tid & 31;
  const int s  = tid >> 5;
  const int r0 = 4 * s;

  float a0 = tin[r0][cc + 3],     a1 = tin[r0][cc + 4],     a2 = tin[r0][cc + 5];
  float b0 = tin[r0 + 1][cc + 3], b1 = tin[r0 + 1][cc + 4], b2 = tin[r0 + 1][cc + 5];
  float o[4];
  float ssq = 0.f;
#pragma unroll
  for (int i = 0; i < 4; i++) {
    float c0 = tin[r0 + 2 + i][cc + 3];
    float c1 = tin[r0 + 2 + i][cc + 4];
    float c2 = tin[r0 + 2 + i][cc + 5];
    float acc = wv[0] * a0 + wv[1] * a1 + wv[2] * a2
              + wv[3] * b0 + wv[4] * b1 + wv[5] * b2
              + wv[6] * c0 + wv[7] * c1 + wv[8] * c2;
    o[i] = acc;
    ssq += acc * acc;
    a0 = b0; a1 = b1; a2 = b2;
    b0 = c0; b1 = c1; b2 = c2;
  }

  float inv = 1.f;
  if (part != 2) {
    float t = ssq;
    t += __shfl_xor(t, 1, 64);
    t += __shfl_xor(t, 2, 64);
    t += __shfl_xor(t, 4, 64);
    t += __shfl_xor(t, 32, 64);
    inv = 1.f / fmaxf(sqrtf(t), 1e-12f);
  }

  ushort_t* dst = (part == 0) ? qpo : ((part == 1) ? kpo : vpo);
  int n = (ty * 4 + (s >> 1)) * NWH + tx * 4 + (cc >> 3);
  int prow0 = r0 & 7;
  int pcol  = cc & 7;
  ushort_t* op = dst + ((size_t)bc * NW + n) * P2;
#pragma unroll
  for (int i = 0; i < 4; i++)
    op[(prow0 + i) * 8 + pcol] = f2bf(o[i] * inv);
}

// ---------------- K3: fused window attention + pe (bubble-fill heterogeneous blocks) ---------
// blocks [0, 1152): attention (r23 path, unchanged). blocks [1152, 8064): pe path
// (r21 k4 semantics: vp -> conv1+gelu masked -> conv2 -> bf16 pe), LDS aliased.
__device__ __forceinline__ void stage_v(const ushort_t* __restrict__ vb,
                                        ushort_t* __restrict__ dst, int tid) {
#pragma unroll
  for (int it = 0; it < 3; it++) {
    int idx = tid + it * 192;
    if (it < 2 || idx < 512) {
      int kv = idx & 63, c = idx >> 6;
      s16x8 v = *(const s16x8*)(vb + kv * 64 + c * 8);
#pragma unroll
      for (int t = 0; t < 8; t++) {
        int p = c * 8 + t;
        dst[p * 64 + (kv ^ ((p & 7) << 3))] = (ushort_t)v[t];
      }
    }
  }
}

__device__ __forceinline__ void stage_k(const ushort_t* __restrict__ kb,
                                        ushort_t* __restrict__ dst, int tid) {
#pragma unroll
  for (int it = 0; it < 3; it++) {
    int idx = tid + it * 192;
    if (it < 2 || idx < 512) {
      int kv = idx >> 3, c = idx & 7;
      s16x8 v = *(const s16x8*)(kb + kv * 64 + c * 8);
      *(s16x8*)&dst[kv * 64 + ((c * 8) ^ ((kv & 7) << 3))] = v;
    }
  }
}

__global__ __launch_bounds__(192, 2) void k3_attn_pe(const ushort_t* __restrict__ qp,
                                                     const ushort_t* __restrict__ kp,
                                                     const ushort_t* __restrict__ vp,
                                                     const float* __restrict__ scale_p,
                                                     ushort_t* __restrict__ o_p,
                                                     const float* __restrict__ w1p,
                                                     const float* __restrict__ w2p,
                                                     ushort_t* __restrict__ pe) {
  __shared__ ushort_t SMEM[16384];   // 32 KB; attn: VT[2]|KT[2]; pe: vt/gt floats
  const int tid = threadIdx.x;

  if (blockIdx.x < BB * CC * 6) {
    // ================= attention path (identical to r23) =================
    const int lane = tid & 63;
    const int wv   = tid >> 6;
    const int lq   = lane & 15;
    const int g    = lane >> 4;
    const int bid  = blockIdx.x;
    const int gw   = (bid & 7) * 144 + (bid >> 3);
    const int bc   = gw / 6;
    const int qch  = gw % 6;
    const int q0   = qch * 96 + wv * 32;
    const float sl = scale_p[0];

    const ushort_t* qpb = qp + (size_t)bc * NW * 64;
    const ushort_t* kpb = kp + (size_t)bc * NW * 64;
    const ushort_t* vpb = vp + (size_t)bc * NW * 64;
    ushort_t* VT0 = SMEM;           // [2][4096]
    ushort_t* KT0 = SMEM + 8192;    // [2][4096]

    s16x8 qf[2][2];
#pragma unroll
    for (int nt = 0; nt < 2; nt++)
#pragma unroll
      for (int ks = 0; ks < 2; ks++)
        qf[nt][ks] = *(const s16x8*)(qpb + (size_t)(q0 + nt * 16 + lq) * 64 + ks * 32 + g * 8);

    const f32x4 zf = {0.f, 0.f, 0.f, 0.f};
    f32x4 Oa[2][4];
#pragma unroll
    for (int a = 0; a < 2; a++)
#pragma unroll
      for (int b2 = 0; b2 < 4; b2++) Oa[a][b2] = zf;
    float lsum[2] = {0.f, 0.f};

    stage_k(kpb, KT0, tid);
    stage_v(vpb, VT0, tid);
    __syncthreads();

    const int s0 = lq + ((lane & 16) << 1);

    for (int kt = 0; kt < 9; kt++) {
      const int cur = kt & 1;
      ushort_t* VTc = VT0 + cur * 4096;
      ushort_t* KTc = KT0 + cur * 4096;
      if (kt < 8) {
        stage_k(kpb + (kt + 1) * 4096, KT0 + (cur ^ 1) * 4096, tid);
        stage_v(vpb + (kt + 1) * 4096, VT0 + (cur ^ 1) * 4096, tid);
      }

      f32x4 s[4][2];
#pragma unroll
      for (int a = 0; a < 4; a++)
#pragma unroll
        for (int b2 = 0; b2 < 2; b2++) s[a][b2] = zf;
#pragma unroll
      for (int ks = 0; ks < 2; ks++) {
        s16x8 kf[4];
#pragma unroll
        for (int mt = 0; mt < 4; mt++)
          kf[mt] = *(const s16x8*)&KTc[(mt * 16 + lq) * 64 + ((ks * 32 + g * 8) ^ ((lq & 7) << 3))];
#pragma unroll
        for (int mt = 0; mt < 4; mt++)
#pragma unroll
          for (int nt = 0; nt < 2; nt++)
            s[mt][nt] = __builtin_amdgcn_mfma_f32_16x16x32_bf16(kf[mt], qf[nt][ks], s[mt][nt], 0, 0, 0);
      }

      unsigned pk[2][4][2];
#pragma unroll
      for (int nt = 0; nt < 2; nt++) {
        float rs = 0.f;
#pragma unroll
        for (int mt = 0; mt < 4; mt++) {
          float e0 = __expf(s[mt][nt][0] * sl);
          float e1 = __expf(s[mt][nt][1] * sl);
          float e2 = __expf(s[mt][nt][2] * sl);
          float e3 = __expf(s[mt][nt][3] * sl);
          rs += (e0 + e1) + (e2 + e3);
          pk[nt][mt][0] = (unsigned)f2bf(e0) | ((unsigned)f2bf(e1) << 16);
          pk[nt][mt][1] = (unsigned)f2bf(e2) | ((unsigned)f2bf(e3) << 16);
        }
        lsum[nt] += rs;
      }

#pragma unroll
      for (int ks2 = 0; ks2 < 2; ks2++) {
        s16x8 vf[4];
#pragma unroll
        for (int ntd = 0; ntd < 4; ntd++) {
          int p = ntd * 16 + lq;
          vf[ntd] = *(const s16x8*)&VTc[p * 64 + ((ks2 * 32 + g * 8) ^ ((p & 7) << 3))];
        }
#pragma unroll
        for (int qt = 0; qt < 2; qt++) {
          union { s16x8 v; unsigned u[4]; } af;
#pragma unroll
          for (int w = 0; w < 4; w++) {
            int src = s0 + ((w >> 1) << 4);
            unsigned lo = __shfl(pk[qt][2 * ks2 + 0][w & 1], src, 64);
            unsigned hi = __shfl(pk[qt][2 * ks2 + 1][w & 1], src, 64);
            af.u[w] = (lane & 32) ? hi : lo;
          }
#pragma unroll
          for (int ntd = 0; ntd < 4; ntd++)
            Oa[qt][ntd] = __builtin_amdgcn_mfma_f32_16x16x32_bf16(af.v, vf[ntd], Oa[qt][ntd], 0, 0, 0);
        }
      }
      __syncthreads();
    }

    float inv[2];
#pragma unroll
    for (int nt = 0; nt < 2; nt++) {
      float v = lsum[nt];
      v += __shfl_xor(v, 16, 64);
      v += __shfl_xor(v, 32, 64);
      inv[nt] = 1.f / v;
    }
    ushort_t* ob = o_p + ((size_t)bc * NW + q0) * 64;
#pragma unroll
    for (int qt = 0; qt < 2; qt++) {
#pragma unroll
      for (int r = 0; r < 4; r++) {
        float iv = __shfl(inv[qt], g * 4 + r, 64);
#pragma unroll
        for (int ntd = 0; ntd < 4; ntd++)
          ob[(qt * 16 + g * 4 + r) * 64 + ntd * 16 + lq] = f2bf(Oa[qt][ntd][r] * iv);
      }
    }
  } else {
    // ================= pe path (r21 k4 semantics, 192-thread) =================
    float* vt = (float*)SMEM;          // [36][38] = 1368 f
    float* gt = ((float*)SMEM) + 1368; // [34][36] = 1224 f  (10.4 KB total)
    int pid = blockIdx.x - BB * CC * 6;
    int b = pid / (CC * 36);
    int rem = pid % (CC * 36);
    int c = rem / 36;
    int tile = rem % 36;
    int ty = tile / 6, tx = tile % 6;
    const ushort_t* src = vp + ((size_t)(b * CC + c)) * NW * P2;
    int h0 = ty * 32 - 2, w0 = tx * 32 - 2;
    for (int idx = tid; idx < 36 * 36; idx += 192) {
      int r = idx / 36, cc2 = idx % 36;
      int h = h0 + r, w = w0 + cc2;
      float v = 0.f;
      if (h >= 0 && h < HH && w >= 0 && w < WWI) {
        int n2 = (h >> 3) * NWH + (w >> 3);
        int p2 = ((h & 7) << 3) | (w & 7);
        v = bf2f(src[(size_t)n2 * P2 + p2]);
      }
      vt[r * 38 + cc2] = v;
    }
    float w1[9], w2[9];
#pragma unroll
    for (int i = 0; i < 9; i++) { w1[i] = w1p[c * 9 + i]; w2[i] = w2p[c * 9 + i]; }
    __syncthreads();
    for (int idx = tid; idx < 34 * 34; idx += 192) {
      int r = idx / 34, cc2 = idx % 34;
      int gh = ty * 32 + r - 1, gw2 = tx * 32 + cc2 - 1;
      float a = 0.f;
#pragma unroll
      for (int dy = 0; dy < 3; dy++)
#pragma unroll
        for (int dx = 0; dx < 3; dx++)
          a += w1[dy * 3 + dx] * vt[(r + dy) * 38 + cc2 + dx];
      float gv = 0.5f * a * (1.f + erff(a * 0.70710678118f));
      gt[r * 36 + cc2] = (gh >= 0 && gh < HH && gw2 >= 0 && gw2 < WWI) ? gv : 0.f;
    }
    __syncthreads();
    ushort_t* dst = pe + ((size_t)(b * CC + c)) * HWQ;
    for (int idx = tid; idx < 1024; idx += 192) {
      int hl = idx >> 5, wl = idx & 31;
      float a = 0.f;
#pragma unroll
      for (int dy = 0; dy < 3; dy++)
#pragma unroll
        for (int dx = 0; dx < 3; dx++)
          a += w2[dy * 3 + dx] * gt[(hl + dy) * 36 + wl + dx];
      dst[(ty * 32 + hl) * WWI + tx * 32 + wl] = f2bf(a);
    }
  }
}

// ---------------- K5: out = proj(xo) + bias + pe, bf16 MFMA GEMM, bf16 inputs ----------------
__global__ __launch_bounds__(384) void k5_proj(const ushort_t* __restrict__ o_p,
                                               const ushort_t* __restrict__ pwb,
                                               const float* __restrict__ pb,
                                               const ushort_t* __restrict__ pe,
                                               float* __restrict__ out) {
  __shared__ ushort_t xo[96][104];
  const int bx = blockIdx.x;
  const int b = bx / NW, n = bx % NW;
  const int wr = n / NWH, wc = n % NWH;
  const int tid = threadIdx.x;
#pragma unroll
  for (int it = 0; it < 2; it++) {
    int idx = tid + it * 384;
    int c = idx >> 3, ch = idx & 7;
    *(s16x8*)&xo[c][ch * 8] =
        *(const s16x8*)(o_p + ((size_t)(b * CC + c) * NW + n) * P2 + ch * 8);
  }
  __syncthreads();
  const int lane = tid & 63, wv = tid >> 6;
  const int lq = lane & 15, g = lane >> 4;
  const int o = wv * 16 + lq;
  s16x8 bfr[3];
#pragma unroll
  for (int kk = 0; kk < 3; kk++)
    bfr[kk] = *(const s16x8*)(pwb + (size_t)o * 96 + kk * 32 + g * 8);
  const f32x4 zf = {0.f, 0.f, 0.f, 0.f};
  f32x4 acc[4] = {zf, zf, zf, zf};
#pragma unroll
  for (int kk = 0; kk < 3; kk++) {
#pragma unroll
    for (int mt = 0; mt < 4; mt++) {
      s16x8 a;
#pragma unroll
      for (int j = 0; j < 8; j++)
        a[j] = (short)xo[kk * 32 + g * 8 + j][mt * 16 + lq];
      acc[mt] = __builtin_amdgcn_mfma_f32_16x16x32_bf16(a, bfr[kk], acc[mt], 0, 0, 0);
    }
  }
  const float pbv = pb[o];
  const ushort_t* per = pe + ((size_t)(b * CC + o)) * HWQ;
  float* ob = out + (size_t)b * HWQ * CC;
#pragma unroll
  for (int mt = 0; mt < 4; mt++) {
    int p = mt * 16 + g * 4;
    int hw = (wr * 8 + (p >> 3)) * WWI + wc * 8 + (p & 7);
    s16x4 pv = *(const s16x4*)(per + hw);
#pragma unroll
    for (int r = 0; r < 4; r++)
      ob[(size_t)(hw + r) * CC + o] = acc[mt][r] + pbv + bf2f((ushort_t)pv[r]);
  }
}

extern "C" void kernel_launch(void* const* d_in, const int* in_sizes, int n_in,
                              void* d_out, int out_size, void* d_ws, size_t ws_size,
                              hipStream_t stream) {
  const float* x        = (const float*)d_in[0];
  const float* qkv_w    = (const float*)d_in[1];
  const float* qkv_dw_w = (const float*)d_in[2];
  const float* scale    = (const float*)d_in[3];
  const float* proj_w   = (const float*)d_in[4];
  const float* proj_b   = (const float*)d_in[5];
  const float* pe_w1    = (const float*)d_in[6];
  const float* pe_w2    = (const float*)d_in[7];
  float* ws = (float*)d_ws;

  // ws layout in FLOAT units (unchanged from r23).
  ushort_t* qkv_bf = (ushort_t*)ws;               // [0,        10616832) f
  ushort_t* o_p    = (ushort_t*)ws;               // alias: 7,077,888 u16 (qkv_bf dead after k2)
  ushort_t* pe     = (ushort_t*)(ws + 10616832);  // 7,077,888 u16
  ushort_t* qp     = (ushort_t*)(ws + 17694720);
  ushort_t* kp     = (ushort_t*)(ws + 21233664);
  ushort_t* vp     = (ushort_t*)(ws + 24772608);
  ushort_t* qwb    = (ushort_t*)(ws + 28311552);  // 27,648 u16
  ushort_t* pwb    = (ushort_t*)(ws + 28325376);  //  9,216 u16 -> 113.3 MB total

  float* out = (float*)d_out;

  hipLaunchKernelGGL(k0_cvtw2, dim3(144), dim3(256), 0, stream,
                     qkv_w, qwb, C3 * CC, proj_w, pwb, CC * CC);
  hipLaunchKernelGGL(k1_qkv, dim3((BB * HWQ) / 64), dim3(384), 0, stream, x, qwb, qkv_bf);
  hipLaunchKernelGGL(k2_dw, dim3(BB * C3 * 36), dim3(256), 0, stream,
                     qkv_bf, qkv_dw_w, qp, kp, vp);
  hipLaunchKernelGGL(k3_attn_pe, dim3(BB * CC * 6 + BB * CC * 36), dim3(192), 0, stream,
                     qp, kp, vp, scale, o_p, pe_w1, pe_w2, pe);
  hipLaunchKernelGGL(k5_proj, dim3(BB * NW), dim3(384), 0, stream, o_p, pwb, proj_b, pe, out);
}

// Round 25
// 150.695 us; speedup vs baseline: 1.0536x; 1.0536x over previous
//
#include <hip/hip_runtime.h>
#include <hip/hip_bf16.h>
#include <math.h>

#define BB   2
#define CC   96
#define C3   288
#define HH   192
#define WWI  192
#define HWQ  (HH*WWI)   // 36864
#define NWH  24
#define NW   576
#define P2   64

typedef float v4f  __attribute__((ext_vector_type(4)));
typedef float f32x4 __attribute__((ext_vector_type(4)));
typedef short s16x8 __attribute__((ext_vector_type(8)));
typedef short s16x4 __attribute__((ext_vector_type(4)));
typedef unsigned short ushort_t;

static __device__ __forceinline__ unsigned short f2bf(float f) {
  __hip_bfloat16 h = __float2bfloat16(f);
  return *reinterpret_cast<unsigned short*>(&h);
}
static __device__ __forceinline__ float bf2f(ushort_t u) {
  union { unsigned u32; float f; } x;
  x.u32 = ((unsigned)u) << 16;
  return x.f;
}

// ---------------- K0: convert both weight arrays to bf16 (one launch) ----------------
__global__ __launch_bounds__(256) void k0_cvtw2(const float* __restrict__ a,
                                                ushort_t* __restrict__ ab, int na,
                                                const float* __restrict__ b,
                                                ushort_t* __restrict__ bb, int nb) {
  int i = blockIdx.x * 256 + threadIdx.x;
  if (i < na) ab[i] = f2bf(a[i]);
  int j = i - na;
  if (j >= 0 && j < nb) bb[j] = f2bf(b[j]);
}

// ---------------- K1: qkv = conv1x1(x), bf16 MFMA GEMM, LDS-shared A-tile ----------------
__global__ __launch_bounds__(384) void k1_qkv(const float* __restrict__ x,
                                              const ushort_t* __restrict__ qwb,
                                              ushort_t* __restrict__ qkv_bf) {
  __shared__ ushort_t XA[64][104];   // 104-pad: row stride 208 B = 13x16 B (aligned b128)
  const int tid  = threadIdx.x;
  const int lane = tid & 63;
  const int wv   = tid >> 6;       // 0..5
  const int lq   = lane & 15;
  const int g    = lane >> 4;      // 0..3
  const int m0   = blockIdx.x * 64;
  const int b    = m0 / HWQ;
  const int hwb  = m0 % HWQ;
  const int n0   = wv * 48;

#pragma unroll
  for (int it = 0; it < 4; it++) {
    int idx = tid + it * 384;
    int px = idx / 24, c4 = idx % 24;
    v4f xx = *(const v4f*)(x + (size_t)(m0 + px) * 96 + c4 * 4);
    s16x4 st;
#pragma unroll
    for (int t = 0; t < 4; t++) st[t] = (short)f2bf(xx[t]);
    *(s16x4*)&XA[px][c4 * 4] = st;
  }
  __syncthreads();

  const f32x4 zf = {0.f, 0.f, 0.f, 0.f};
  f32x4 acc[4][3];
#pragma unroll
  for (int mt = 0; mt < 4; mt++)
#pragma unroll
    for (int nt = 0; nt < 3; nt++) acc[mt][nt] = zf;

#pragma unroll
  for (int kk = 0; kk < 3; kk++) {
    s16x8 af[4];
#pragma unroll
    for (int mt = 0; mt < 4; mt++)
      af[mt] = *(const s16x8*)&XA[mt * 16 + lq][kk * 32 + g * 8];
    s16x8 bfr[3];
#pragma unroll
    for (int nt = 0; nt < 3; nt++)
      bfr[nt] = *(const s16x8*)(qwb + (size_t)(n0 + nt * 16 + lq) * 96 + kk * 32 + g * 8);
#pragma unroll
    for (int mt = 0; mt < 4; mt++)
#pragma unroll
      for (int nt = 0; nt < 3; nt++)
        acc[mt][nt] = __builtin_amdgcn_mfma_f32_16x16x32_bf16(af[mt], bfr[nt], acc[mt][nt], 0, 0, 0);
  }

  ushort_t* ob = qkv_bf + (size_t)b * C3 * HWQ;
#pragma unroll
  for (int nt = 0; nt < 3; nt++) {
    int o = n0 + nt * 16 + lq;
#pragma unroll
    for (int mt = 0; mt < 4; mt++) {
      s16x4 st;
#pragma unroll
      for (int t = 0; t < 4; t++) st[t] = (short)f2bf(acc[mt][nt][t]);
      *(s16x4*)(ob + (size_t)o * HWQ + hwb + mt * 16 + g * 4) = st;
    }
  }
}

// ---------------- K2: depthwise 3x3 + patchify; q/k: fused l2norm; v: fused pe path ----------------
__global__ __launch_bounds__(256) void k2_dw(const ushort_t* __restrict__ qkv_pre,
                                             const float* __restrict__ dww,
                                             const float* __restrict__ w1p,
                                             const float* __restrict__ w2p,
                                             ushort_t* __restrict__ qpo, ushort_t* __restrict__ kpo,
                                             ushort_t* __restrict__ vpo, ushort_t* __restrict__ pe) {
  __shared__ float lds[4336];   // v: tin38[38*44] | vt[36*40] | gt[34*36]; qk: tin34[34*40]
  int bx  = blockIdx.x;
  int b   = bx / (C3 * 36);
  int rem = bx % (C3 * 36);
  int ch  = rem / 36;
  int tile = rem % 36;
  int ty = tile / 6, tx = tile % 6;
  int tid = threadIdx.x;
  const ushort_t* src = qkv_pre + ((size_t)b * C3 + ch) * HWQ;
  const int part = ch / CC, c96 = ch % CC;
  const int bc = b * CC + c96;
  const int w0 = tx * 32;
  float wv[9];
#pragma unroll
  for (int i = 0; i < 9; i++) wv[i] = dww[ch * 9 + i];

  if (part != 2) {
    float* tin = lds;   // [34][40]
    const int h0 = ty * 32 - 1;
    for (int idx = tid; idx < 340; idx += 256) {
      int r = idx / 10, u = idx - r * 10;
      int h = h0 + r;
      bool hok = (h >= 0 && h < HH);
      if (u < 8) {
        v4f f = {0.f, 0.f, 0.f, 0.f};
        if (hok) {
          s16x4 raw = *(const s16x4*)(src + h * WWI + w0 + u * 4);
#pragma unroll
          for (int t = 0; t < 4; t++) f[t] = bf2f((ushort_t)raw[t]);
        }
        *(v4f*)&tin[r * 40 + 4 + u * 4] = f;
      } else {
        int w = (u == 8) ? (w0 - 1) : (w0 + 32);
        int cdst = (u == 8) ? 3 : 36;
        float f = 0.f;
        if (hok && w >= 0 && w < WWI) f = bf2f(src[h * WWI + w]);
        tin[r * 40 + cdst] = f;
      }
    }
    __syncthreads();

    const int cc = tid & 31;
    const int s  = tid >> 5;
    const int r0 = 4 * s;
    float a0 = tin[r0 * 40 + cc + 3],       a1 = tin[r0 * 40 + cc + 4],       a2 = tin[r0 * 40 + cc + 5];
    float b0 = tin[(r0 + 1) * 40 + cc + 3], b1 = tin[(r0 + 1) * 40 + cc + 4], b2 = tin[(r0 + 1) * 40 + cc + 5];
    float o[4];
    float ssq = 0.f;
#pragma unroll
    for (int i = 0; i < 4; i++) {
      float c0 = tin[(r0 + 2 + i) * 40 + cc + 3];
      float c1 = tin[(r0 + 2 + i) * 40 + cc + 4];
      float c2 = tin[(r0 + 2 + i) * 40 + cc + 5];
      float acc = wv[0] * a0 + wv[1] * a1 + wv[2] * a2
                + wv[3] * b0 + wv[4] * b1 + wv[5] * b2
                + wv[6] * c0 + wv[7] * c1 + wv[8] * c2;
      o[i] = acc;
      ssq += acc * acc;
      a0 = b0; a1 = b1; a2 = b2;
      b0 = c0; b1 = c1; b2 = c2;
    }
    float t = ssq;
    t += __shfl_xor(t, 1, 64);
    t += __shfl_xor(t, 2, 64);
    t += __shfl_xor(t, 4, 64);
    t += __shfl_xor(t, 32, 64);
    float inv = 1.f / fmaxf(sqrtf(t), 1e-12f);

    ushort_t* dst = (part == 0) ? qpo : kpo;
    int n = (ty * 4 + (s >> 1)) * NWH + tx * 4 + (cc >> 3);
    int prow0 = r0 & 7;
    int pcol  = cc & 7;
    ushort_t* op = dst + ((size_t)bc * NW + n) * P2;
#pragma unroll
    for (int i = 0; i < 4; i++)
      op[(prow0 + i) * 8 + pcol] = f2bf(o[i] * inv);
  } else {
    float* tin38 = lds;          // [38][44]
    float* vt    = lds + 1672;   // [36][40]
    float* gt    = lds + 3112;   // [34][36]
    float w1[9], w2[9];
#pragma unroll
    for (int i = 0; i < 9; i++) { w1[i] = w1p[c96 * 9 + i]; w2[i] = w2p[c96 * 9 + i]; }
    const int h0v = ty * 32 - 3;
    for (int idx = tid; idx < 380; idx += 256) {
      int r = idx / 10, u = idx - r * 10;
      int h = h0v + r;
      bool hok = (h >= 0 && h < HH);
      if (u < 8) {
        v4f f = {0.f, 0.f, 0.f, 0.f};
        if (hok) {
          s16x4 raw = *(const s16x4*)(src + h * WWI + w0 + u * 4);
#pragma unroll
          for (int t = 0; t < 4; t++) f[t] = bf2f((ushort_t)raw[t]);
        }
        *(v4f*)&tin38[r * 44 + 4 + u * 4] = f;
      } else if (u == 8) {
#pragma unroll
        for (int t = 0; t < 3; t++) {
          int w = w0 - 3 + t;
          float f = 0.f;
          if (hok && w >= 0) f = bf2f(src[h * WWI + w]);
          tin38[r * 44 + 1 + t] = f;
        }
      } else {
#pragma unroll
        for (int t = 0; t < 3; t++) {
          int w = w0 + 32 + t;
          float f = 0.f;
          if (hok && w < WWI) f = bf2f(src[h * WWI + w]);
          tin38[r * 44 + 36 + t] = f;
        }
      }
    }
    __syncthreads();

    {
      const int cv = tid % 36, sv = tid / 36;
      if (sv < 6) {
        const int rv0 = sv * 6;
        const int wq = tx * 32 - 2 + cv;
        const bool wok = (wq >= 0) & (wq < WWI);
        float a0 = tin38[rv0 * 44 + cv + 1],       a1 = tin38[rv0 * 44 + cv + 2],       a2 = tin38[rv0 * 44 + cv + 3];
        float b0 = tin38[(rv0 + 1) * 44 + cv + 1], b1 = tin38[(rv0 + 1) * 44 + cv + 2], b2 = tin38[(rv0 + 1) * 44 + cv + 3];
#pragma unroll
        for (int i = 0; i < 6; i++) {
          float c0 = tin38[(rv0 + 2 + i) * 44 + cv + 1];
          float c1 = tin38[(rv0 + 2 + i) * 44 + cv + 2];
          float c2 = tin38[(rv0 + 2 + i) * 44 + cv + 3];
          float acc = wv[0] * a0 + wv[1] * a1 + wv[2] * a2
                    + wv[3] * b0 + wv[4] * b1 + wv[5] * b2
                    + wv[6] * c0 + wv[7] * c1 + wv[8] * c2;
          int h = ty * 32 - 2 + rv0 + i;
          vt[(rv0 + i) * 40 + cv] = (wok & (h >= 0) & (h < HH)) ? acc : 0.f;
          a0 = b0; a1 = b1; a2 = b2;
          b0 = c0; b1 = c1; b2 = c2;
        }
      }
    }
    __syncthreads();

    for (int idx = tid; idx < 1024; idx += 256) {
      int hl = idx >> 5, wl = idx & 31;
      float v = vt[(hl + 2) * 40 + wl + 2];
      int n = (ty * 4 + (hl >> 3)) * NWH + tx * 4 + (wl >> 3);
      int p = ((hl & 7) << 3) | (wl & 7);
      vpo[((size_t)bc * NW + n) * P2 + p] = f2bf(v);
    }

    {
      const int cg = tid % 34, sg = tid / 34;
      if (sg < 6) {
        const int rg0 = sg * 6;
        const int gw2 = tx * 32 - 1 + cg;
        const bool gok = (gw2 >= 0) & (gw2 < WWI);
        float a0 = vt[rg0 * 40 + cg],       a1 = vt[rg0 * 40 + cg + 1],       a2 = vt[rg0 * 40 + cg + 2];
        float b0 = vt[(rg0 + 1) * 40 + cg], b1 = vt[(rg0 + 1) * 40 + cg + 1], b2 = vt[(rg0 + 1) * 40 + cg + 2];
#pragma unroll
        for (int i = 0; i < 6; i++) {
          int rg = rg0 + i;
          if (rg >= 34) break;
          float c0 = vt[(rg + 2) * 40 + cg];
          float c1 = vt[(rg + 2) * 40 + cg + 1];
          float c2 = vt[(rg + 2) * 40 + cg + 2];
          float acc = w1[0] * a0 + w1[1] * a1 + w1[2] * a2
                    + w1[3] * b0 + w1[4] * b1 + w1[5] * b2
                    + w1[6] * c0 + w1[7] * c1 + w1[8] * c2;
          float gv = 0.5f * acc * (1.f + erff(acc * 0.70710678118f));
          int gh = ty * 32 - 1 + rg;
          gt[rg * 36 + cg] = (gok & (gh >= 0) & (gh < HH)) ? gv : 0.f;
          a0 = b0; a1 = b1; a2 = b2;
          b0 = c0; b1 = c1; b2 = c2;
        }
      }
    }
    __syncthreads();

    {
      const int cc = tid & 31;
      const int s  = tid >> 5;
      const int r0 = 4 * s;
      float a0 = gt[r0 * 36 + cc],       a1 = gt[r0 * 36 + cc + 1],       a2 = gt[r0 * 36 + cc + 2];
      float b0 = gt[(r0 + 1) * 36 + cc], b1 = gt[(r0 + 1) * 36 + cc + 1], b2 = gt[(r0 + 1) * 36 + cc + 2];
      ushort_t* dst = pe + ((size_t)bc) * HWQ;
#pragma unroll
      for (int i = 0; i < 4; i++) {
        float c0 = gt[(r0 + 2 + i) * 36 + cc];
        float c1 = gt[(r0 + 2 + i) * 36 + cc + 1];
        float c2 = gt[(r0 + 2 + i) * 36 + cc + 2];
        float acc = w2[0] * a0 + w2[1] * a1 + w2[2] * a2
                  + w2[3] * b0 + w2[4] * b1 + w2[5] * b2
                  + w2[6] * c0 + w2[7] * c1 + w2[8] * c2;
        dst[(ty * 32 + r0 + i) * WWI + tx * 32 + cc] = f2bf(acc);
        a0 = b0; a1 = b1; a2 = b2;
        b0 = c0; b1 = c1; b2 = c2;
      }
    }
  }
}

// ---------------- K3: window attention, bf16 MFMA, 32 q/wave, K+V in LDS, XCD swizzle ----------------
__device__ __forceinline__ void stage_v(const ushort_t* __restrict__ vb,
                                        ushort_t* __restrict__ dst, int tid) {
#pragma unroll
  for (int it = 0; it < 3; it++) {
    int idx = tid + it * 192;
    if (it < 2 || idx < 512) {
      int kv = idx & 63, c = idx >> 6;
      s16x8 v = *(const s16x8*)(vb + kv * 64 + c * 8);
#pragma unroll
      for (int t = 0; t < 8; t++) {
        int p = c * 8 + t;
        dst[p * 64 + (kv ^ ((p & 7) << 3))] = (ushort_t)v[t];
      }
    }
  }
}

__device__ __forceinline__ void stage_k(const ushort_t* __restrict__ kb,
                                        ushort_t* __restrict__ dst, int tid) {
#pragma unroll
  for (int it = 0; it < 3; it++) {
    int idx = tid + it * 192;
    if (it < 2 || idx < 512) {
      int kv = idx >> 3, c = idx & 7;
      s16x8 v = *(const s16x8*)(kb + kv * 64 + c * 8);
      *(s16x8*)&dst[kv * 64 + ((c * 8) ^ ((kv & 7) << 3))] = v;
    }
  }
}

__global__ __launch_bounds__(192, 2) void k3_attn(const ushort_t* __restrict__ qp,
                                                  const ushort_t* __restrict__ kp,
                                                  const ushort_t* __restrict__ vp,
                                                  const float* __restrict__ scale_p,
                                                  ushort_t* __restrict__ o_p) {
  __shared__ ushort_t VT[2][4096];
  __shared__ ushort_t KT[2][4096];
  const int tid  = threadIdx.x;
  const int lane = tid & 63;
  const int wv   = tid >> 6;       // wave 0..2
  const int lq   = lane & 15;
  const int g    = lane >> 4;      // 0..3
  const int bid  = blockIdx.x;     // 1152 blocks, 1152%8==0
  const int gw   = (bid & 7) * 144 + (bid >> 3);
  const int bc   = gw / 6;
  const int qch  = gw % 6;
  const int q0   = qch * 96 + wv * 32;   // 32 q-rows per wave
  const float sl = scale_p[0];

  const ushort_t* qpb = qp + (size_t)bc * NW * 64;
  const ushort_t* kpb = kp + (size_t)bc * NW * 64;
  const ushort_t* vpb = vp + (size_t)bc * NW * 64;

  s16x8 qf[2][2];
#pragma unroll
  for (int nt = 0; nt < 2; nt++)
#pragma unroll
    for (int ks = 0; ks < 2; ks++)
      qf[nt][ks] = *(const s16x8*)(qpb + (size_t)(q0 + nt * 16 + lq) * 64 + ks * 32 + g * 8);

  const f32x4 zf = {0.f, 0.f, 0.f, 0.f};
  f32x4 Oa[2][4];
#pragma unroll
  for (int a = 0; a < 2; a++)
#pragma unroll
    for (int b2 = 0; b2 < 4; b2++) Oa[a][b2] = zf;
  float lsum[2] = {0.f, 0.f};

  stage_k(kpb, KT[0], tid);
  stage_v(vpb, VT[0], tid);
  __syncthreads();

  const int s0 = lq + ((lane & 16) << 1);

  for (int kt = 0; kt < 9; kt++) {
    const int cur = kt & 1;
    if (kt < 8) {
      stage_k(kpb + (kt + 1) * 4096, KT[cur ^ 1], tid);
      stage_v(vpb + (kt + 1) * 4096, VT[cur ^ 1], tid);
    }

    f32x4 s[4][2];
#pragma unroll
    for (int a = 0; a < 4; a++)
#pragma unroll
      for (int b2 = 0; b2 < 2; b2++) s[a][b2] = zf;
#pragma unroll
    for (int ks = 0; ks < 2; ks++) {
      s16x8 kf[4];
#pragma unroll
      for (int mt = 0; mt < 4; mt++)
        kf[mt] = *(const s16x8*)&KT[cur][(mt * 16 + lq) * 64 + ((ks * 32 + g * 8) ^ ((lq & 7) << 3))];
#pragma unroll
      for (int mt = 0; mt < 4; mt++)
#pragma unroll
        for (int nt = 0; nt < 2; nt++)
          s[mt][nt] = __builtin_amdgcn_mfma_f32_16x16x32_bf16(kf[mt], qf[nt][ks], s[mt][nt], 0, 0, 0);
    }

    unsigned pk[2][4][2];
#pragma unroll
    for (int nt = 0; nt < 2; nt++) {
      float rs = 0.f;
#pragma unroll
      for (int mt = 0; mt < 4; mt++) {
        float e0 = __expf(s[mt][nt][0] * sl);
        float e1 = __expf(s[mt][nt][1] * sl);
        float e2 = __expf(s[mt][nt][2] * sl);
        float e3 = __expf(s[mt][nt][3] * sl);
        rs += (e0 + e1) + (e2 + e3);
        pk[nt][mt][0] = (unsigned)f2bf(e0) | ((unsigned)f2bf(e1) << 16);
        pk[nt][mt][1] = (unsigned)f2bf(e2) | ((unsigned)f2bf(e3) << 16);
      }
      lsum[nt] += rs;
    }

#pragma unroll
    for (int ks2 = 0; ks2 < 2; ks2++) {
      s16x8 vf[4];
#pragma unroll
      for (int ntd = 0; ntd < 4; ntd++) {
        int p = ntd * 16 + lq;
        vf[ntd] = *(const s16x8*)&VT[cur][p * 64 + ((ks2 * 32 + g * 8) ^ ((p & 7) << 3))];
      }
#pragma unroll
      for (int qt = 0; qt < 2; qt++) {
        union { s16x8 v; unsigned u[4]; } af;
#pragma unroll
        for (int w = 0; w < 4; w++) {
          int src = s0 + ((w >> 1) << 4);
          unsigned lo = __shfl(pk[qt][2 * ks2 + 0][w & 1], src, 64);
          unsigned hi = __shfl(pk[qt][2 * ks2 + 1][w & 1], src, 64);
          af.u[w] = (lane & 32) ? hi : lo;
        }
#pragma unroll
        for (int ntd = 0; ntd < 4; ntd++)
          Oa[qt][ntd] = __builtin_amdgcn_mfma_f32_16x16x32_bf16(af.v, vf[ntd], Oa[qt][ntd], 0, 0, 0);
      }
    }
    __syncthreads();
  }

  float inv[2];
#pragma unroll
  for (int nt = 0; nt < 2; nt++) {
    float v = lsum[nt];
    v += __shfl_xor(v, 16, 64);
    v += __shfl_xor(v, 32, 64);
    inv[nt] = 1.f / v;
  }
  ushort_t* ob = o_p + ((size_t)bc * NW + q0) * 64;
#pragma unroll
  for (int qt = 0; qt < 2; qt++) {
#pragma unroll
    for (int r = 0; r < 4; r++) {
      float iv = __shfl(inv[qt], g * 4 + r, 64);
#pragma unroll
      for (int ntd = 0; ntd < 4; ntd++)
        ob[(qt * 16 + g * 4 + r) * 64 + ntd * 16 + lq] = f2bf(Oa[qt][ntd][r] * iv);
    }
  }
}

// ---------------- K5: out = proj(xo) + bias + pe, bf16 MFMA GEMM, bf16 inputs ----------------
__global__ __launch_bounds__(384) void k5_proj(const ushort_t* __restrict__ o_p,
                                               const ushort_t* __restrict__ pwb,
                                               const float* __restrict__ pb,
                                               const ushort_t* __restrict__ pe,
                                               float* __restrict__ out) {
  __shared__ ushort_t xo[96][104];
  const int bx = blockIdx.x;
  const int b = bx / NW, n = bx % NW;
  const int wr = n / NWH, wc = n % NWH;
  const int tid = threadIdx.x;
#pragma unroll
  for (int it = 0; it < 2; it++) {
    int idx = tid + it * 384;   // 768 chunks of 8 bf16
    int c = idx >> 3, ch = idx & 7;
    *(s16x8*)&xo[c][ch * 8] =
        *(const s16x8*)(o_p + ((size_t)(b * CC + c) * NW + n) * P2 + ch * 8);
  }
  __syncthreads();
  const int lane = tid & 63, wv = tid >> 6;   // 6 waves; wave wv owns o-tile wv
  const int lq = lane & 15, g = lane >> 4;
  const int o = wv * 16 + lq;
  s16x8 bfr[3];
#pragma unroll
  for (int kk = 0; kk < 3; kk++)
    bfr[kk] = *(const s16x8*)(pwb + (size_t)o * 96 + kk * 32 + g * 8);
  const f32x4 zf = {0.f, 0.f, 0.f, 0.f};
  f32x4 acc[4] = {zf, zf, zf, zf};
#pragma unroll
  for (int kk = 0; kk < 3; kk++) {
#pragma unroll
    for (int mt = 0; mt < 4; mt++) {
      s16x8 a;
#pragma unroll
      for (int j = 0; j < 8; j++)
        a[j] = (short)xo[kk * 32 + g * 8 + j][mt * 16 + lq];
      acc[mt] = __builtin_amdgcn_mfma_f32_16x16x32_bf16(a, bfr[kk], acc[mt], 0, 0, 0);
    }
  }
  const float pbv = pb[o];
  const ushort_t* per = pe + ((size_t)(b * CC + o)) * HWQ;
  float* ob = out + (size_t)b * HWQ * CC;
#pragma unroll
  for (int mt = 0; mt < 4; mt++) {
    int p = mt * 16 + g * 4;
    int hw = (wr * 8 + (p >> 3)) * WWI + wc * 8 + (p & 7);
    s16x4 pv = *(const s16x4*)(per + hw);
#pragma unroll
    for (int r = 0; r < 4; r++)
      ob[(size_t)(hw + r) * CC + o] = acc[mt][r] + pbv + bf2f((ushort_t)pv[r]);
  }
}

extern "C" void kernel_launch(void* const* d_in, const int* in_sizes, int n_in,
                              void* d_out, int out_size, void* d_ws, size_t ws_size,
                              hipStream_t stream) {
  const float* x        = (const float*)d_in[0];
  const float* qkv_w    = (const float*)d_in[1];
  const float* qkv_dw_w = (const float*)d_in[2];
  const float* scale    = (const float*)d_in[3];
  const float* proj_w   = (const float*)d_in[4];
  const float* proj_b   = (const float*)d_in[5];
  const float* pe_w1    = (const float*)d_in[6];
  const float* pe_w2    = (const float*)d_in[7];
  float* ws = (float*)d_ws;

  // ws layout in FLOAT units.
  ushort_t* qkv_bf = (ushort_t*)ws;               // [0,        10616832) f
  ushort_t* o_p    = (ushort_t*)ws;               // alias: 7,077,888 u16 (qkv_bf dead after k2)
  ushort_t* pe     = (ushort_t*)(ws + 10616832);  // 7,077,888 u16
  ushort_t* qp     = (ushort_t*)(ws + 17694720);
  ushort_t* kp     = (ushort_t*)(ws + 21233664);
  ushort_t* vp     = (ushort_t*)(ws + 24772608);
  ushort_t* qwb    = (ushort_t*)(ws + 28311552);  // 27,648 u16
  ushort_t* pwb    = (ushort_t*)(ws + 28325376);  //  9,216 u16 -> 113.3 MB total

  float* out = (float*)d_out;

  hipLaunchKernelGGL(k0_cvtw2, dim3(144), dim3(256), 0, stream,
                     qkv_w, qwb, C3 * CC, proj_w, pwb, CC * CC);
  hipLaunchKernelGGL(k1_qkv, dim3((BB * HWQ) / 64), dim3(384), 0, stream, x, qwb, qkv_bf);
  hipLaunchKernelGGL(k2_dw, dim3(BB * C3 * 36), dim3(256), 0, stream,
                     qkv_bf, qkv_dw_w, pe_w1, pe_w2, qp, kp, vp, pe);
  hipLaunchKernelGGL(k3_attn, dim3(BB * CC * 6), dim3(192), 0, stream, qp, kp, vp, scale, o_p);
  hipLaunchKernelGGL(k5_proj, dim3(BB * NW), dim3(384), 0, stream, o_p, pwb, proj_b, pe, out);
}